// Round 3
// baseline (155.025 us; speedup 1.0000x reference)
//
#include <hip/hip_runtime.h>

// VP_lattice reverse step, B = 2^20 rows. Round-6:
//  R5 counters: dur 42.6us, VALU 15%, HBM 31%-of-achievable, Occ 48% ->
//  still latency-bound (all pipes idle). Fix: memory-level parallelism.
//  - ROWS=2 per thread (512 rows/block): epilogue inputs 3x float4 per
//    array (was 6x float2), t as int2, stores 3x float4. Half the VMEM
//    instructions per row, 2x bytes in flight per thread.
//  - ALL global loads (plat stage, table copy, t, epilogue) issued before
//    the single barrier -> load latency overlaps the barrier wait.
//  - LDS 30.6KB (18.4 plat + 12.1 tables) -> 5 blocks/CU;
//    __launch_bounds__(256,5) caps VGPR ~102 to realize 20 waves/CU.
//  - Math identical to R5 (trig eigenvalues + Hoger-Carlson sqrtm,
//    Hastings acos + __cosf, folded schedule coefs in d_ws).

#define NUM_STEPS 1000
#define TBL 1008          // 1001 rounded up to x16 floats
#define BLOCK 256
#define ROWS 2
#define RPB (BLOCK * ROWS)   // 512 rows per block

// ---------------- schedule pre-kernel (runs once, ~2us) ----------------
__global__ __launch_bounds__(256) void sched_kernel(
    const float* __restrict__ alpha_bars,
    const float* __restrict__ betas,
    const float* __restrict__ sigmas,
    float* __restrict__ ws)          // layout: [A[TBL] | B[TBL] | S[TBL]]
{
    int j = blockIdx.x * blockDim.x + threadIdx.x;
    if (j >= TBL) return;
    if (j <= NUM_STEPS) {
        float beta_last = betas[NUM_STEPS - 1];              // betas[-2]
        float alpha = 1.0f - fminf(betas[j], beta_last);     // clamp_min
        float coef  = 1.0f / sqrtf(alpha + 1e-8f);
        float scale = (1.0f - alpha) / sqrtf(1.0f - alpha_bars[j] + 1e-8f);
        ws[j]           = coef * (1.0f - scale);             // A
        ws[TBL + j]     = 0.5f * coef * scale;               // B
        ws[2 * TBL + j] = (j > 1) ? sigmas[j] : 0.0f;        // S (z-gated)
    } else {
        ws[j] = 0.0f; ws[TBL + j] = 0.0f; ws[2 * TBL + j] = 0.0f;
    }
}

// ---- per-row math: vec = upper-tri of sqrtm(A^T A), R5-identical ----
__device__ __forceinline__ void sqrtm_vec(const float* __restrict__ pr,
                                          float vv[6])
{
    float a00 = pr[0], a01 = pr[1], a02 = pr[2];
    float a10 = pr[3], a11 = pr[4], a12 = pr[5];
    float a20 = pr[6], a21 = pr[7], a22 = pr[8];

    float m00 = a00*a00 + a10*a10 + a20*a20;
    float m01 = a00*a01 + a10*a11 + a20*a21;
    float m02 = a00*a02 + a10*a12 + a20*a22;
    float m11 = a01*a01 + a11*a11 + a21*a21;
    float m12 = a01*a02 + a11*a12 + a21*a22;
    float m22 = a02*a02 + a12*a12 + a22*a22;

    float q  = (m00 + m11 + m22) * (1.0f/3.0f);
    float b00 = m00 - q, b11 = m11 - q, b22 = m22 - q;
    float p1 = m01*m01 + m02*m02 + m12*m12;
    float p2 = b00*b00 + b11*b11 + b22*b22 + 2.0f*p1;
    float p  = sqrtf(p2 * (1.0f/6.0f));
    float detB = b00*(b11*b22 - m12*m12)
               - m01*(m01*b22 - m12*m02)
               + m02*(m01*m12 - b11*m02);
    float pinv = __fdividef(1.0f, fmaxf(p, 1e-20f));
    float r = 0.5f * detB * pinv * pinv * pinv;
    r = fminf(fmaxf(r, -1.0f), 1.0f);

    float ar = fabsf(r);
    float sq = sqrtf(1.0f - ar);
    float pl = 1.5707288f + ar * (-0.2121144f + ar * (0.0742610f - ar * 0.0187293f));
    float ac = sq * pl;
    float acr = (r >= 0.0f) ? ac : (3.14159265358979f - ac);
    float phi = acr * (1.0f/3.0f);                           // [0, pi/3]
    float mu1 = q + 2.0f*p*__cosf(phi);
    float mu3 = q + 2.0f*p*__cosf(phi + 2.0943951023931953f);
    float mu2 = 3.0f*q - mu1 - mu3;
    float l1 = sqrtf(fmaxf(mu1, 0.0f));
    float l2 = sqrtf(fmaxf(mu2, 0.0f));
    float l3 = sqrtf(fmaxf(mu3, 0.0f));

    float IU   = l1 + l2 + l3;
    float IIU  = l1*(l2 + l3) + l2*l3;
    float IIIU = l1*l2*l3;
    float denom = (l1 + l2) * (l1 + l3) * (l2 + l3);
    float dinv  = __fdividef(1.0f, fmaxf(denom, 1e-25f));
    float sd = (IU*IU - IIU) * dinv;
    float td = IU * IIIU * dinv;
    float nd = -dinv;

    float mm00 = m00*m00 + m01*m01 + m02*m02;
    float mm01 = m00*m01 + m01*m11 + m02*m12;
    float mm02 = m00*m02 + m01*m12 + m02*m22;
    float mm11 = m01*m01 + m11*m11 + m12*m12;
    float mm12 = m01*m02 + m11*m12 + m12*m22;
    float mm22 = m02*m02 + m12*m12 + m22*m22;

    vv[0] = nd*mm00 + sd*m00 + td;
    vv[1] = nd*mm01 + sd*m01;
    vv[2] = nd*mm02 + sd*m02;
    vv[3] = nd*mm11 + sd*m11 + td;
    vv[4] = nd*mm12 + sd*m12;
    vv[5] = nd*mm22 + sd*m22 + td;
}

// ---------------- main kernel ----------------
__global__ __launch_bounds__(BLOCK, 5) void vp_lattice_kernel(
    const float* __restrict__ lt,
    const float* __restrict__ pl0,
    const float* __restrict__ plat,
    const float* __restrict__ alpha_bars,
    const float* __restrict__ betas,
    const float* __restrict__ sigmas,
    const float* __restrict__ z_noise,
    const int*   __restrict__ t,
    float* __restrict__ out,
    int n,
    const float* __restrict__ ws,
    int use_ws)
{
    __shared__ __align__(16) float sA[TBL];
    __shared__ __align__(16) float sB[TBL];
    __shared__ __align__(16) float sS[TBL];
    __shared__ __align__(16) float platT[RPB * 9];   // 18432 B

    const int tid = threadIdx.x;
    const int rowBase = blockIdx.x * RPB;
    int rem = n - rowBase; if (rem > RPB) rem = RPB;
    const bool full = (rem == RPB);

    // ---- 1) plat stage: coalesced float4 (1152 per block) ----
    if (full) {
        const float4* g9 = reinterpret_cast<const float4*>(plat + (size_t)rowBase * 9);
        float4*       s9 = reinterpret_cast<float4*>(platT);
#pragma unroll
        for (int k = 0; k < 5; ++k) {
            int j = tid + k * BLOCK;
            if (j < RPB * 9 / 4) s9[j] = g9[j];
        }
    } else {
        for (int j = tid; j < rem * 9; j += BLOCK)
            platT[j] = plat[(size_t)rowBase * 9 + j];
    }

    // ---- 2) schedule tables into LDS ----
    if (use_ws) {
        const float4* w4 = reinterpret_cast<const float4*>(ws);
        float4* a4 = reinterpret_cast<float4*>(sA);
        float4* b4 = reinterpret_cast<float4*>(sB);
        float4* s4 = reinterpret_cast<float4*>(sS);
        for (int j = tid; j < TBL / 4; j += BLOCK) {
            a4[j] = w4[j];
            b4[j] = w4[TBL / 4 + j];
            s4[j] = w4[2 * (TBL / 4) + j];
        }
    } else {
        float beta_last = betas[NUM_STEPS - 1];
        for (int j = tid; j < TBL; j += BLOCK) {
            float A = 0.0f, Bc = 0.0f, S = 0.0f;
            if (j <= NUM_STEPS) {
                float alpha = 1.0f - fminf(betas[j], beta_last);
                float coef  = 1.0f / sqrtf(alpha + 1e-8f);
                float scale = (1.0f - alpha) / sqrtf(1.0f - alpha_bars[j] + 1e-8f);
                A  = coef * (1.0f - scale);
                Bc = 0.5f * coef * scale;
                S  = (j > 1) ? sigmas[j] : 0.0f;
            }
            sA[j] = A; sB[j] = Bc; sS[j] = S;
        }
    }

    // ---- 3) t pair + epilogue inputs, issued BEFORE the barrier ----
    const int r0 = rowBase + 2 * tid;        // this thread's first row
    int ti0 = 0, ti1 = 0;
    float4 lv0, lv1, lv2, pv0, pv1, pv2, zv0, zv1, zv2;
    lv0 = lv1 = lv2 = pv0 = pv1 = pv2 = zv0 = zv1 = zv2 = make_float4(0.f,0.f,0.f,0.f);

    if (full) {
        int2 tp = *(reinterpret_cast<const int2*>(t + rowBase) + tid);
        ti0 = tp.x; ti1 = tp.y;
        const float4* lp = reinterpret_cast<const float4*>(lt      + (size_t)rowBase * 6) + tid * 3;
        const float4* pp = reinterpret_cast<const float4*>(pl0     + (size_t)rowBase * 6) + tid * 3;
        const float4* zp = reinterpret_cast<const float4*>(z_noise + (size_t)rowBase * 6) + tid * 3;
        lv0 = lp[0]; lv1 = lp[1]; lv2 = lp[2];
        pv0 = pp[0]; pv1 = pp[1]; pv2 = pp[2];
        zv0 = zp[0]; zv1 = zp[1]; zv2 = zp[2];
    } else {
        // guarded scalar path (tail block only; never hit at B=2^20)
        float lbuf[12] = {0}, pbuf[12] = {0}, zbuf[12] = {0};
        for (int c = 0; c < 12; ++c) {
            size_t idx = (size_t)r0 * 6 + c;
            if (r0 * 6 + c < rem * 6 + rowBase * 6 && (r0 + c / 6) < n) {
                lbuf[c] = lt[idx]; pbuf[c] = pl0[idx]; zbuf[c] = z_noise[idx];
            }
        }
        lv0 = make_float4(lbuf[0], lbuf[1], lbuf[2], lbuf[3]);
        lv1 = make_float4(lbuf[4], lbuf[5], lbuf[6], lbuf[7]);
        lv2 = make_float4(lbuf[8], lbuf[9], lbuf[10], lbuf[11]);
        pv0 = make_float4(pbuf[0], pbuf[1], pbuf[2], pbuf[3]);
        pv1 = make_float4(pbuf[4], pbuf[5], pbuf[6], pbuf[7]);
        pv2 = make_float4(pbuf[8], pbuf[9], pbuf[10], pbuf[11]);
        zv0 = make_float4(zbuf[0], zbuf[1], zbuf[2], zbuf[3]);
        zv1 = make_float4(zbuf[4], zbuf[5], zbuf[6], zbuf[7]);
        zv2 = make_float4(zbuf[8], zbuf[9], zbuf[10], zbuf[11]);
        if (r0     < n) ti0 = t[r0];
        if (r0 + 1 < n) ti1 = t[r0 + 1];
    }

    __syncthreads();   // the ONE barrier

    if (r0 >= n) return;

    // ---- row 0 ----
    float va[6];
    sqrtm_vec(platT + tid * 18, va);
    float A0 = sA[ti0], B0 = sB[ti0], S0 = sS[ti0];

    float o[12];
    o[0] = A0*lv0.x + B0*(va[0] + pv0.x) + S0*zv0.x;
    o[1] = A0*lv0.y + B0*(va[1] + pv0.y) + S0*zv0.y;
    o[2] = A0*lv0.z + B0*(va[2] + pv0.z) + S0*zv0.z;
    o[3] = A0*lv0.w + B0*(va[3] + pv0.w) + S0*zv0.w;
    o[4] = A0*lv1.x + B0*(va[4] + pv1.x) + S0*zv1.x;
    o[5] = A0*lv1.y + B0*(va[5] + pv1.y) + S0*zv1.y;

    // ---- row 1 ----
    bool has1 = (r0 + 1 < n);
    if (has1) {
        float vb[6];
        sqrtm_vec(platT + tid * 18 + 9, vb);
        float A1 = sA[ti1], B1 = sB[ti1], S1 = sS[ti1];
        o[6]  = A1*lv1.z + B1*(vb[0] + pv1.z) + S1*zv1.z;
        o[7]  = A1*lv1.w + B1*(vb[1] + pv1.w) + S1*zv1.w;
        o[8]  = A1*lv2.x + B1*(vb[2] + pv2.x) + S1*zv2.x;
        o[9]  = A1*lv2.y + B1*(vb[3] + pv2.y) + S1*zv2.y;
        o[10] = A1*lv2.z + B1*(vb[4] + pv2.z) + S1*zv2.z;
        o[11] = A1*lv2.w + B1*(vb[5] + pv2.w) + S1*zv2.w;
    }

    // ---- store ----
    if (full) {
        float4* op = reinterpret_cast<float4*>(out + (size_t)rowBase * 6) + tid * 3;
        op[0] = make_float4(o[0], o[1], o[2],  o[3]);
        op[1] = make_float4(o[4], o[5], o[6],  o[7]);
        op[2] = make_float4(o[8], o[9], o[10], o[11]);
    } else {
        int lim = has1 ? 12 : 6;
        for (int c = 0; c < lim; ++c) out[(size_t)r0 * 6 + c] = o[c];
    }
}

extern "C" void kernel_launch(void* const* d_in, const int* in_sizes, int n_in,
                              void* d_out, int out_size, void* d_ws, size_t ws_size,
                              hipStream_t stream) {
    const float* lt         = (const float*)d_in[0];
    const float* pl0        = (const float*)d_in[1];
    const float* plat       = (const float*)d_in[2];
    const float* alpha_bars = (const float*)d_in[3];
    const float* betas      = (const float*)d_in[4];
    const float* sigmas     = (const float*)d_in[5];
    const float* z_noise    = (const float*)d_in[6];
    const int*   t          = (const int*)d_in[7];
    float* out = (float*)d_out;
    float* ws  = (float*)d_ws;

    int n = in_sizes[0] / 6;   // B rows
    int use_ws = (ws != nullptr && ws_size >= (size_t)(3 * TBL * sizeof(float)));

    if (use_ws) {
        sched_kernel<<<(TBL + 255) / 256, 256, 0, stream>>>(alpha_bars, betas, sigmas, ws);
    }
    int grid = (n + RPB - 1) / RPB;
    vp_lattice_kernel<<<grid, BLOCK, 0, stream>>>(
        lt, pl0, plat, alpha_bars, betas, sigmas, z_noise, t, out, n, ws, use_ws);
}

// Round 4
// 153.656 us; speedup vs baseline: 1.0089x; 1.0089x over previous
//
#include <hip/hip_runtime.h>

// VP_lattice reverse step, B = 2^20 rows. Round-7:
//  R6 post-mortem: __launch_bounds__(256,5) + 36 live floats across the
//  barrier made the compiler SINK the prefetch loads below the barrier
//  (VGPR=44, no spill traffic) -> lost all MLP, occ 38%, dur 51us.
//  R5's (256,6)/VGPR=36 likely had the same pathology milder.
//  R7 = R5 memory pattern, scheduling fixed:
//   - Pre-barrier: ONLY plat stage + table copy + t load (7 VMEM in the
//     barrier drain, was 19).
//   - Post-barrier: issue 9x float2 epilogue loads + 3 LDS table gathers
//     FIRST, then sqrtm (~250cy dep chain) hides their (L3-hit) latency.
//   - __launch_bounds__(256) with NO wave minimum: VGPR floats to the
//     natural ~90 -> ~5 waves/SIMD, no load sinking.
//   - 1 row/thread (stride-9 LDS reads = conflict-free).
//  Math identical to R5 (passed, absmax 0.0156): trig eigenvalues +
//  Hoger-Carlson sqrtm, Hastings acos + __cosf, folded coefs via d_ws.

#define NUM_STEPS 1000
#define TBL 1008          // 1001 rounded up to x16 floats
#define BLOCK 256

// ---------------- schedule pre-kernel (runs once, ~2us) ----------------
__global__ __launch_bounds__(256) void sched_kernel(
    const float* __restrict__ alpha_bars,
    const float* __restrict__ betas,
    const float* __restrict__ sigmas,
    float* __restrict__ ws)          // layout: [A[TBL] | B[TBL] | S[TBL]]
{
    int j = blockIdx.x * blockDim.x + threadIdx.x;
    if (j >= TBL) return;
    if (j <= NUM_STEPS) {
        float beta_last = betas[NUM_STEPS - 1];              // betas[-2]
        float alpha = 1.0f - fminf(betas[j], beta_last);     // clamp_min
        float coef  = 1.0f / sqrtf(alpha + 1e-8f);
        float scale = (1.0f - alpha) / sqrtf(1.0f - alpha_bars[j] + 1e-8f);
        ws[j]           = coef * (1.0f - scale);             // A
        ws[TBL + j]     = 0.5f * coef * scale;               // B
        ws[2 * TBL + j] = (j > 1) ? sigmas[j] : 0.0f;        // S (z-gated)
    } else {
        ws[j] = 0.0f; ws[TBL + j] = 0.0f; ws[2 * TBL + j] = 0.0f;
    }
}

// ---------------- main kernel ----------------
__global__ __launch_bounds__(BLOCK) void vp_lattice_kernel(
    const float* __restrict__ lt,
    const float* __restrict__ pl0,
    const float* __restrict__ plat,
    const float* __restrict__ alpha_bars,
    const float* __restrict__ betas,
    const float* __restrict__ sigmas,
    const float* __restrict__ z_noise,
    const int*   __restrict__ t,
    float* __restrict__ out,
    int n,
    const float* __restrict__ ws,
    int use_ws)
{
    __shared__ __align__(16) float sA[TBL];
    __shared__ __align__(16) float sB[TBL];
    __shared__ __align__(16) float sS[TBL];
    __shared__ __align__(16) float platT[BLOCK * 9];   // 9216 B

    const int tid = threadIdx.x;
    const int rowBase = blockIdx.x * BLOCK;
    int rem = n - rowBase; if (rem > BLOCK) rem = BLOCK;
    const bool full = (rem == BLOCK);

    // ---- 1) plat stage: coalesced float4 (576 per block) ----
    if (full) {
        const float4* g9 = reinterpret_cast<const float4*>(plat + (size_t)rowBase * 9);
        float4*       s9 = reinterpret_cast<float4*>(platT);
#pragma unroll
        for (int k = 0; k < 3; ++k) {                 // 576 float4 / 256 threads
            int j = tid + k * BLOCK;
            if (j < BLOCK * 9 / 4) s9[j] = g9[j];
        }
    } else {
        for (int j = tid; j < rem * 9; j += BLOCK)
            platT[j] = plat[(size_t)rowBase * 9 + j];
    }

    // ---- 2) schedule tables into LDS ----
    if (use_ws) {
        const float4* w4 = reinterpret_cast<const float4*>(ws);
        float4* a4 = reinterpret_cast<float4*>(sA);
        float4* b4 = reinterpret_cast<float4*>(sB);
        float4* s4 = reinterpret_cast<float4*>(sS);
        for (int j = tid; j < TBL / 4; j += BLOCK) {  // 252 -> 1 iter/thread
            a4[j] = w4[j];
            b4[j] = w4[TBL / 4 + j];
            s4[j] = w4[2 * (TBL / 4) + j];
        }
    } else {
        float beta_last = betas[NUM_STEPS - 1];
        for (int j = tid; j < TBL; j += BLOCK) {
            float A = 0.0f, Bc = 0.0f, S = 0.0f;
            if (j <= NUM_STEPS) {
                float alpha = 1.0f - fminf(betas[j], beta_last);
                float coef  = 1.0f / sqrtf(alpha + 1e-8f);
                float scale = (1.0f - alpha) / sqrtf(1.0f - alpha_bars[j] + 1e-8f);
                A  = coef * (1.0f - scale);
                Bc = 0.5f * coef * scale;
                S  = (j > 1) ? sigmas[j] : 0.0f;
            }
            sA[j] = A; sB[j] = Bc; sS[j] = S;
        }
    }

    // ---- 3) t gather (needed immediately after barrier for table reads) ----
    int ti = (tid < rem) ? t[rowBase + tid] : 0;

    __syncthreads();   // drains the 7 pre-barrier VMEM + ds_writes

    if (tid >= rem) return;

    // ---- 4) epilogue loads issued FIRST (latency hidden under sqrtm) ----
    size_t b6 = (size_t)(rowBase + tid) * 6;
    const float2* lt2 = reinterpret_cast<const float2*>(lt + b6);
    const float2* p02 = reinterpret_cast<const float2*>(pl0 + b6);
    const float2* zn2 = reinterpret_cast<const float2*>(z_noise + b6);
    float2 lw0 = lt2[0], lw1 = lt2[1], lw2 = lt2[2];
    float2 pw0 = p02[0], pw1 = p02[1], pw2 = p02[2];
    float2 zw0 = zn2[0], zw1 = zn2[1], zw2 = zn2[2];

    // ---- 5) table gathers (LDS, random addr ~2-way = free) ----
    float A  = sA[ti];
    float Bc = sB[ti];
    float S  = sS[ti];

    // ---- 6) load A (3x3) from LDS; stride 9 (odd) = conflict-free ----
    const float* pr = platT + tid * 9;
    float a00 = pr[0], a01 = pr[1], a02 = pr[2];
    float a10 = pr[3], a11 = pr[4], a12 = pr[5];
    float a20 = pr[6], a21 = pr[7], a22 = pr[8];

    // ---- M = A^T A (symmetric PSD) ----
    float m00 = a00*a00 + a10*a10 + a20*a20;
    float m01 = a00*a01 + a10*a11 + a20*a21;
    float m02 = a00*a02 + a10*a12 + a20*a22;
    float m11 = a01*a01 + a11*a11 + a21*a21;
    float m12 = a01*a02 + a11*a12 + a21*a22;
    float m22 = a02*a02 + a12*a12 + a22*a22;

    // ---- eigenvalues: cancellation-free trig form ----
    float q  = (m00 + m11 + m22) * (1.0f/3.0f);
    float b00 = m00 - q, b11 = m11 - q, b22 = m22 - q;
    float p1 = m01*m01 + m02*m02 + m12*m12;
    float p2 = b00*b00 + b11*b11 + b22*b22 + 2.0f*p1;
    float p  = sqrtf(p2 * (1.0f/6.0f));
    float detB = b00*(b11*b22 - m12*m12)
               - m01*(m01*b22 - m12*m02)
               + m02*(m01*m12 - b11*m02);
    float pinv = __fdividef(1.0f, fmaxf(p, 1e-20f));
    float r = 0.5f * detB * pinv * pinv * pinv;
    r = fminf(fmaxf(r, -1.0f), 1.0f);

    // acos via Hastings poly (AS 4.4.45, |err|<=6.8e-5 rad), then native cos
    float ar = fabsf(r);
    float sq = sqrtf(1.0f - ar);
    float pl = 1.5707288f + ar * (-0.2121144f + ar * (0.0742610f - ar * 0.0187293f));
    float ac = sq * pl;
    float acr = (r >= 0.0f) ? ac : (3.14159265358979f - ac);
    float phi = acr * (1.0f/3.0f);                           // [0, pi/3]
    float mu1 = q + 2.0f*p*__cosf(phi);                      // largest
    float mu3 = q + 2.0f*p*__cosf(phi + 2.0943951023931953f);// smallest
    float mu2 = 3.0f*q - mu1 - mu3;
    float l1 = sqrtf(fmaxf(mu1, 0.0f));
    float l2 = sqrtf(fmaxf(mu2, 0.0f));
    float l3 = sqrtf(fmaxf(mu3, 0.0f));

    // ---- U = sqrtm(M), Hoger-Carlson (inverse-free) ----
    float IU   = l1 + l2 + l3;
    float IIU  = l1*(l2 + l3) + l2*l3;
    float IIIU = l1*l2*l3;
    float denom = (l1 + l2) * (l1 + l3) * (l2 + l3);
    float dinv  = __fdividef(1.0f, fmaxf(denom, 1e-25f));
    float sd = (IU*IU - IIU) * dinv;      // coefficient of M
    float td = IU * IIIU * dinv;          // coefficient of Id
    float nd = -dinv;                     // coefficient of M^2

    float mm00 = m00*m00 + m01*m01 + m02*m02;
    float mm01 = m00*m01 + m01*m11 + m02*m12;
    float mm02 = m00*m02 + m01*m12 + m02*m22;
    float mm11 = m01*m01 + m11*m11 + m12*m12;
    float mm12 = m01*m02 + m11*m12 + m12*m22;
    float mm22 = m02*m02 + m12*m12 + m22*m22;

    float v0 = nd*mm00 + sd*m00 + td;     // L00
    float v1 = nd*mm01 + sd*m01;          // L01
    float v2 = nd*mm02 + sd*m02;          // L02
    float v3 = nd*mm11 + sd*m11 + td;     // L11
    float v4 = nd*mm12 + sd*m12;          // L12
    float v5 = nd*mm22 + sd*m22 + td;     // L22

    // ---- 7) epilogue: out = A*lt + B*(vec + pl0) + S*z ----
    float2 o0, o1, o2;
    o0.x = A*lw0.x + Bc*(v0 + pw0.x) + S*zw0.x;
    o0.y = A*lw0.y + Bc*(v1 + pw0.y) + S*zw0.y;
    o1.x = A*lw1.x + Bc*(v2 + pw1.x) + S*zw1.x;
    o1.y = A*lw1.y + Bc*(v3 + pw1.y) + S*zw1.y;
    o2.x = A*lw2.x + Bc*(v4 + pw2.x) + S*zw2.x;
    o2.y = A*lw2.y + Bc*(v5 + pw2.y) + S*zw2.y;

    float2* out2 = reinterpret_cast<float2*>(out + b6);
    out2[0] = o0;
    out2[1] = o1;
    out2[2] = o2;
}

extern "C" void kernel_launch(void* const* d_in, const int* in_sizes, int n_in,
                              void* d_out, int out_size, void* d_ws, size_t ws_size,
                              hipStream_t stream) {
    const float* lt         = (const float*)d_in[0];
    const float* pl0        = (const float*)d_in[1];
    const float* plat       = (const float*)d_in[2];
    const float* alpha_bars = (const float*)d_in[3];
    const float* betas      = (const float*)d_in[4];
    const float* sigmas     = (const float*)d_in[5];
    const float* z_noise    = (const float*)d_in[6];
    const int*   t          = (const int*)d_in[7];
    float* out = (float*)d_out;
    float* ws  = (float*)d_ws;

    int n = in_sizes[0] / 6;   // B rows
    int use_ws = (ws != nullptr && ws_size >= (size_t)(3 * TBL * sizeof(float)));

    if (use_ws) {
        sched_kernel<<<(TBL + 255) / 256, 256, 0, stream>>>(alpha_bars, betas, sigmas, ws);
    }
    int grid = (n + BLOCK - 1) / BLOCK;
    vp_lattice_kernel<<<grid, BLOCK, 0, stream>>>(
        lt, pl0, plat, alpha_bars, betas, sigmas, z_noise, t, out, n, ws, use_ws);
}